// Round 7
// baseline (200.646 us; speedup 1.0000x reference)
//
#include <hip/hip_runtime.h>
#include <math.h>

#define TT  1024
#define BB  2048
#define FF  11
#define PP  256
#define NG  100
#define NCH 32           // chunks over T
#define LCH (TT / NCH)   // 32 steps per chunk

typedef float f32x2 __attribute__((ext_vector_type(2)));
// align-4 vector loads: records are 44 B apart, only dword-aligned
typedef float f32x4u __attribute__((ext_vector_type(4), aligned(4)));
typedef float f32x2u __attribute__((ext_vector_type(2), aligned(4)));

__device__ __forceinline__ float nz(float v) { return (v != v) ? 0.f : v; }

// Branch-free erf, Abramowitz-Stegun 7.1.26, |err| <= 1.5e-7 (abs).
__device__ __forceinline__ float erf_fast(float x) {
    float ax = fabsf(x);
    float t  = __builtin_amdgcn_rcpf(fmaf(0.3275911f, ax, 1.f));
    float y  = fmaf(fmaf(fmaf(fmaf(1.061405429f, t, -1.453152027f), t,
                              1.421413741f), t, -0.284496736f), t, 0.254829592f);
    y *= t;
    float r = fmaf(-y, __expf(-ax * ax), 1.f);
    return copysignf(r, x);
}

// q coefficients for one (t,b) record. Returns (q0, q1, B0=beta*pi1n, B1=beta*pi0n).
__device__ __forceinline__ float4 q_from_rec(
    float a0, float a1, float r0, float r1, float cdc, float cdn,
    float beta, float inv_s)
{
    float u = 0.5f * (1.f + erf_fast((0.0f  - cdc) * inv_s));
    float v = 0.5f * (1.f + erf_fast((-0.1f - cdc) * inv_s));
    float w = 0.5f * (1.f + erf_fast((0.1f  - cdc) * inv_s));
    float inv = 1.f / fmaxf(w - v, 1e-10f);
    float pi0 = fminf(fmaxf((u - v) * inv, 0.f), 1.f);
    float pi1 = fminf(fmaxf((w - u) * inv, 0.f), 1.f);

    u = 0.5f * (1.f + erf_fast((0.0f  - cdn) * inv_s));
    v = 0.5f * (1.f + erf_fast((-0.1f - cdn) * inv_s));
    w = 0.5f * (1.f + erf_fast((0.1f  - cdn) * inv_s));
    inv = 1.f / fmaxf(w - v, 1e-10f);
    float pi0n = fminf(fmaxf((u - v) * inv, 0.f), 1.f);
    float pi1n = fminf(fmaxf((w - u) * inv, 0.f), 1.f);

    float rs = r0 * a0 + r1 * a1;
    float r  = (a0 >= a1) ? rs : 1.f - rs;      // argmax tie -> index 0
    float q0 = pi1 * r + pi0 * (1.f - r);
    float q1 = (2.f * r - 1.f) * (pi0 - pi1);
    if (!((a0 + a1) > 0.f)) { q0 = 1.f; q1 = 0.f; }
    return make_float4(q0, q1, beta * pi1n, beta * pi0n);
}

// per-participant (beta, inv_s) — identical derivation in both kernels.
__device__ __forceinline__ float2 participant(
    const float* __restrict__ x, const float* __restrict__ beta_raw,
    const float* __restrict__ sigma_raw, int b)
{
    int pid = (int)nz(x[(size_t)b * FF + 10]);
    pid = pid < 0 ? 0 : (pid > PP - 1 ? PP - 1 : pid);
    float br = beta_raw[pid];
    float sr = sigma_raw[pid];
    float sp   = fmaxf(br, 0.f) + log1pf(__expf(-fabsf(br)));
    float beta = fminf(fmaxf(sp + 1.f, 1.f), 25.f);
    float sig  = fminf(fmaxf(__builtin_amdgcn_rcpf(1.f + __expf(-sr)) * 0.09f + 0.01f,
                             0.01f), 0.1f);
    return make_float2(beta, 1.f / (sig * 1.41421356237309505f));
}

// ---------------- Phase Aq: direct-load, batched-exchange U (R17 struct) ----
// R18: QC is DELETED (33.6 MB HBM write here + 33.6 MB read in phaseC + 4
// scattered-store instrs/wave). phaseC recomputes qc from x (L3-resident
// after this kernel reads it). Everything else identical to the R17 kernel
// that passed with absmax 0.0078125.
__global__ __launch_bounds__(256, 3) void phaseAq_kernel(
    const float* __restrict__ x, const float* __restrict__ beta_raw,
    const float* __restrict__ sigma_raw, float* __restrict__ UC)
{
    __shared__ float2 sq[4][4][64];              // 8 KB: [wave][r-slot][lane-slot]
    const int lane = threadIdx.x & 63;
    const int wib  = threadIdx.x >> 6;
    const int W    = blockIdx.x * 4 + wib;       // 0..8191
    const int wg   = W & 255;                    // b-octet
    const int c    = W >> 8;                     // chunk 0..31
    const int g    = lane & 7;
    const int sl   = lane >> 3;
    const int b    = wg * 8 + g;
    const int t0   = c * LCH;

    // ---- issue all 4 record loads up-front (dwordx4 + dwordx2 each) ----
    f32x4u r4[4];
    f32x2u r2[4];
    #pragma unroll
    for (int r = 0; r < 4; ++r) {
        const float* rec = x + (size_t)(t0 + 8 * r + sl) * (BB * FF) + b * FF;
        r4[r] = *(const f32x4u*)rec;
        r2[r] = *(const f32x2u*)(rec + 4);
    }

    const float2 pr = participant(x, beta_raw, sigma_raw, b);
    const float beta = pr.x, inv_s = pr.y;

    f32x2 p[7];
    #pragma unroll
    for (int k = 0; k < 7; ++k)
        p[k] = (f32x2){ (float)(sl + 16 * k)     * (1.f / 99.f),
                        (float)(sl + 16 * k + 8) * (1.f / 99.f) };

    // ---- all 4 qc back-to-back: dense independent erf ILP ----
    #pragma unroll
    for (int r = 0; r < 4; ++r) {
        float a0 = nz(r4[r].x), a1 = nz(r4[r].y), r0 = nz(r4[r].z),
              r1 = nz(r4[r].w), dc = nz(r2[r].x), dn = nz(r2[r].y);
        float4 qc = q_from_rec(a0, a1, r0, r1, dc, dn, beta, inv_s);
        sq[wib][r][sl * 8 + g] = make_float2(qc.x, qc.y);
    }
    __builtin_amdgcn_wave_barrier();             // writes before cross-lane reads

    // ---- single exchange pass: 4 independent U-product chains ----
    f32x2 U[4][7];
    #pragma unroll
    for (int r = 0; r < 4; ++r)
        #pragma unroll
        for (int k = 0; k < 7; ++k) U[r][k] = (f32x2){1.f, 1.f};

    #pragma unroll
    for (int j = 0; j < 8; ++j) {
        #pragma unroll
        for (int r = 0; r < 4; ++r) {
            float2 qj = sq[wib][r][j * 8 + g];   // 8 addrs, broadcast reads
            f32x2 qx = { qj.x, qj.x }, qy = { qj.y, qj.y };
            #pragma unroll
            for (int k = 0; k < 7; ++k) {
                f32x2 u = qy * p[k] + qx;        // v_pk_fma_f32
                U[r][k] *= u;                    // v_pk_mul_f32
            }
        }
    }

    // combine partials (reassociation validated R17: absmax unchanged)
    // UC layout [c][i][b]: consecutive lanes (b) -> coalesced float stores
    float* dst = UC + (size_t)c * (NG * BB) + b;
    #pragma unroll
    for (int k = 0; k < 7; ++k) {
        f32x2 Uf = ((U[0][k] * U[1][k]) * U[2][k]) * U[3][k];
        if (k < 6) {
            dst[(size_t)(sl + 16 * k) * BB]     = Uf.x;
            dst[(size_t)(sl + 16 * k + 8) * BB] = Uf.y;
        } else if (sl < 4) {
            dst[(size_t)(sl + 96) * BB] = Uf.x;
        }
    }
}

// ---------------- Phase B: 32-step scan over chunks per (i,b) ----------------
// flat = i*BB + b (layout [c][i][b]); elementwise over flat, coalesced.
__global__ __launch_bounds__(256) void phaseB_kernel(
    const float* __restrict__ UC, float* __restrict__ BE)
{
    const int flat = blockIdx.x * 256 + threadIdx.x;
    float be = 1.f;
    #pragma unroll
    for (int c = 0; c < NCH; ++c) {
        BE[(size_t)c * (BB * NG) + flat] = be;
        float u = UC[(size_t)c * (BB * NG) + flat];
        be = fmaxf(be * u, 1e-30f);              // constant-floor composition
    }
}

// ---------------- Phase C: qc recompute + chunk re-walk ----------------------
// R18: instead of reading QC (33.6 MB HBM), recompute qc from x. Producer
// mapping = phaseAq's exactly (g1 = lane&7 -> b, sl1 = lane>>3 -> step-slot,
// 4 records/lane, dense erf, same op order) -> bit-identical qc values.
// x is L3-resident (92 MB < 256 MB Infinity Cache, read by phaseAq just
// before) so the re-read costs L3 hits, not HBM. Two 16-step tile halves
// (2 KB/wave LDS, reused), wave_barrier-only sync (wave-private tile, same
// idiom as the validated sq exchange). Consumer walk identical to before.
__global__ __launch_bounds__(256, 3) void phaseC_kernel(
    const float* __restrict__ x, const float* __restrict__ beta_raw,
    const float* __restrict__ sigma_raw, const float* __restrict__ BE,
    float* __restrict__ out)
{
    __shared__ float4 tile[4][16][8];            // 8 KB: 16-step qc tile per wave
    const int lane = threadIdx.x & 63;
    const int wib  = threadIdx.x >> 6;
    const int W    = blockIdx.x * 4 + wib;       // 0..8191
    const int wg   = W & 255;                    // b-octet
    const int c    = W >> 8;                     // chunk 0..31
    const int sl   = lane & 7;    // consumer: i-slot
    const int g    = lane >> 3;   // consumer: batch
    const int b    = wg * 8 + g;
    const int g1   = lane & 7;    // producer: batch
    const int sl1  = lane >> 3;   // producer: step-in-block
    const int b1   = wg * 8 + g1;
    const int t0   = c * LCH;

    // ---- issue all 4 record loads up-front (same addresses as phaseAq) ----
    f32x4u r4[4];
    f32x2u r2[4];
    #pragma unroll
    for (int r = 0; r < 4; ++r) {
        const float* rec = x + (size_t)(t0 + 8 * r + sl1) * (BB * FF) + b1 * FF;
        r4[r] = *(const f32x4u*)rec;
        r2[r] = *(const f32x2u*)(rec + 4);
    }

    const float2 pr = participant(x, beta_raw, sigma_raw, b1);
    const float beta = pr.x, inv_s = pr.y;

    f32x2 p3[7];
    #pragma unroll
    for (int k = 0; k < 7; ++k)
        p3[k] = (f32x2){ (float)(sl + 16 * k)     * (1.f / 99.f),
                        (float)(sl + 16 * k + 8) * (1.f / 99.f) };
    const f32x2 clA = { 1e-30f, 1e-30f };
    const f32x2 cl6 = { (sl < 4) ? 1e-30f : 0.f, 0.f };   // pair 6: i=96..111

    // chunk-entry beliefs from BE[c][i][b] (13 scattered loads, once per wave)
    const float* ebase = BE + (size_t)c * (BB * NG) + b;
    f32x2 be[7];
    #pragma unroll
    for (int k = 0; k < 6; ++k)
        be[k] = (f32x2){ ebase[(size_t)(sl + 16 * k) * BB],
                         ebase[(size_t)(sl + 16 * k + 8) * BB] };
    be[6] = (f32x2){ (sl < 4) ? ebase[(size_t)(sl + 96) * BB] : 0.f, 0.f };

    #pragma unroll
    for (int half = 0; half < 2; ++half) {
        // ---- producer: 2 qc dense (bit-identical to phaseAq's), tile write --
        #pragma unroll
        for (int r = 0; r < 2; ++r) {
            const int rr = 2 * half + r;
            float a0 = nz(r4[rr].x), a1 = nz(r4[rr].y), r0 = nz(r4[rr].z),
                  r1 = nz(r4[rr].w), dc = nz(r2[rr].x), dn = nz(r2[rr].y);
            float4 qc = q_from_rec(a0, a1, r0, r1, dc, dn, beta, inv_s);
            tile[wib][8 * r + sl1][g1] = qc;
        }
        __builtin_amdgcn_wave_barrier();         // writes before cross-lane reads

        // ---- consumer: 16-step walk out of the tile ----
        for (int tt = 0; tt < 16; tt += 4) {
            float S[4], Sp[4], Zv[4], Wv[4];
            float4 q4[4];
            #pragma unroll
            for (int j = 0; j < 4; ++j)
                q4[j] = tile[wib][tt + j][g];    // broadcast per address
            #pragma unroll
            for (int j = 0; j < 4; ++j) {
                float4 qf = q4[j];
                f32x2 qx = { qf.x, qf.x }, qy = { qf.y, qf.y };
                #pragma unroll
                for (int k = 0; k < 7; ++k) {
                    f32x2 u = qy * p3[k] + qx;
                    be[k] = __builtin_elementwise_max(be[k] * u,
                                                      (k == 6) ? cl6 : clA);
                }
                f32x2 sA = ((be[0] + be[1]) + (be[2] + be[3]))
                         + ((be[4] + be[5]) + be[6]);
                S[j] = sA.x + sA.y;
                f32x2 a1v = be[0] * p3[0], a2v = be[1] * p3[1];
                a1v = be[2] * p3[2] + a1v;  a2v = be[3] * p3[3] + a2v;
                a1v = be[4] * p3[4] + a1v;  a2v = be[5] * p3[5] + a2v;
                a1v = be[6] * p3[6] + a1v;
                f32x2 aa = a1v + a2v;
                Sp[j] = aa.x + aa.y;
                Zv[j] = qf.z;
                Wv[j] = qf.w;
            }
            #pragma unroll
            for (int j = 0; j < 4; ++j) {
                // 8-lane butterfly sum (pure VALU DPP)
                float st = S[j], sr = Sp[j];
                {
                    int t;
                    t = __builtin_amdgcn_update_dpp(0, __float_as_int(st), 0xB1, 0xF, 0xF, true);
                    st += __int_as_float(t);
                    t = __builtin_amdgcn_update_dpp(0, __float_as_int(sr), 0xB1, 0xF, 0xF, true);
                    sr += __int_as_float(t);
                    t = __builtin_amdgcn_update_dpp(0, __float_as_int(st), 0x4E, 0xF, 0xF, true);
                    st += __int_as_float(t);
                    t = __builtin_amdgcn_update_dpp(0, __float_as_int(sr), 0x4E, 0xF, 0xF, true);
                    sr += __int_as_float(t);
                    t = __builtin_amdgcn_update_dpp(0, __float_as_int(st), 0x141, 0xF, 0xF, true);
                    st += __int_as_float(t);
                    t = __builtin_amdgcn_update_dpp(0, __float_as_int(sr), 0x141, 0xF, 0xF, true);
                    sr += __int_as_float(t);
                }
                float E  = sr * __builtin_amdgcn_rcpf(st);
                float A  = Wv[j] - Zv[j];
                float l0 = fmaf(A, E, Zv[j]);
                float l1 = fmaf(-A, E, Wv[j]);
                if (sl == 0)   // 8 lanes store 8B each; octet is 64B contiguous
                    *(float2*)(out + (size_t)(t0 + 16 * half + tt + j) * (2 * BB) + 2 * b) =
                        make_float2(l0, l1);
            }
        }
        __builtin_amdgcn_wave_barrier();         // reads before tile reuse
    }

    if (c == NCH - 1) {   // final belief carry: out[T*B*2 + b*100 + i]
        float* bel = out + (size_t)TT * BB * 2 + (size_t)b * NG;
        #pragma unroll
        for (int k = 0; k < 6; ++k) {
            bel[sl + 16 * k]     = be[k].x;
            bel[sl + 16 * k + 8] = be[k].y;
        }
        if (sl < 4) bel[sl + 96] = be[6].x;
    }
}

extern "C" void kernel_launch(void* const* d_in, const int* in_sizes, int n_in,
                              void* d_out, int out_size, void* d_ws, size_t ws_size,
                              hipStream_t stream)
{
    const float* x         = (const float*)d_in[0];
    const float* beta_raw  = (const float*)d_in[1];
    const float* sigma_raw = (const float*)d_in[2];
    float* out = (float*)d_out;

    // workspace: UC (26.2 MB) | BE (26.2 MB)  ~= 52 MB (QC deleted, R18)
    char* ws = (char*)d_ws;
    float*  UC = (float*)ws;
    float*  BE = (float*)(ws + (size_t)NCH * BB * NG * 4);

    phaseAq_kernel<<<(BB / 8) * NCH / 4, 256, 0, stream>>>(x, beta_raw, sigma_raw, UC);
    phaseB_kernel<<<(BB * NG) / 256, 256, 0, stream>>>(UC, BE);
    phaseC_kernel<<<(BB / 8) * NCH / 4, 256, 0, stream>>>(x, beta_raw, sigma_raw, BE, out);
}